// Round 14
// baseline (482.130 us; speedup 1.0000x reference)
//
#include <hip/hip_runtime.h>
#include <hip/hip_bf16.h>
#include <stdint.h>

typedef int v4i __attribute__((ext_vector_type(4)));

#define GM 4096
#define GN 16384
#define GK 4096
#define BM 256
#define BN 256
#define BK 64         // i8 bytes per K-step
#define NT (GK / BK)  // 64 K-tiles

__device__ __forceinline__ void gload16(const void* g, void* l) {
  __builtin_amdgcn_global_load_lds(
      (const __attribute__((address_space(1))) void*)g,
      (__attribute__((address_space(3))) void*)l, 16, 0, 0);
}

// ---------------- per-row dynamic quantization -> fragment-ordered Xq2 ----------------
// Xq2[tm][kt][f][lane][16B]: lane l holds row tm*256 + f*16 + (l&15),
// k = kt*64 + (l>>4)*16 .. +16.
__global__ __launch_bounds__(256) void quant_rows(
    const float* __restrict__ x, int8_t* __restrict__ xq2,
    float* __restrict__ xs, int K) {
  const int row = blockIdx.x;
  const int t = threadIdx.x;
  const float4* src = (const float4*)(x + (size_t)row * K) + t * 4;
  float4 v[4];
  float m = 0.f;
#pragma unroll
  for (int i = 0; i < 4; ++i) {
    v[i] = src[i];
    m = fmaxf(m, fmaxf(fmaxf(fabsf(v[i].x), fabsf(v[i].y)),
                       fmaxf(fabsf(v[i].z), fabsf(v[i].w))));
  }
#pragma unroll
  for (int off = 1; off < 64; off <<= 1)
    m = fmaxf(m, __shfl_xor(m, off, 64));
  __shared__ float wmax[4];
  if ((t & 63) == 0) wmax[t >> 6] = m;
  __syncthreads();
  const float gm = fmaxf(fmaxf(wmax[0], wmax[1]), fmaxf(wmax[2], wmax[3]));
  const float scale = (gm + 1e-5f) / 127.0f;  // == ref x_scales
  if (t == 0) xs[row] = scale;
  unsigned packed[4];
#pragma unroll
  for (int i = 0; i < 4; ++i) {
    float fv[4] = {v[i].x, v[i].y, v[i].z, v[i].w};
    unsigned p = 0;
#pragma unroll
    for (int j = 0; j < 4; ++j) {
      int q = (int)rintf(fv[j] / scale);  // RNE, matches np.round
      q = max(-128, min(127, q));
      p |= (unsigned)(q & 0xff) << (8 * j);
    }
    packed[i] = p;
  }
  // thread t owns the 16B chunk at k = t*16: kt = t>>2, kg = t&3
  const int tm = row >> 8, f = (row >> 4) & 15, fr = row & 15;
  const int kt = t >> 2, kg = t & 3;
  int8_t* dst =
      xq2 + ((((size_t)(tm * 64 + kt) * 16 + f) * 64) + fr + 16 * kg) * 16;
  *(int4*)dst =
      make_int4((int)packed[0], (int)packed[1], (int)packed[2], (int)packed[3]);
}

// ------- W int32 [K][N] -> Wt2 int8 in MFMA-fragment order -------
// Wt2[tn][kt][f][lane][16B]: lane l holds col n = tn*256 + f*16 + (l&15),
// k = kt*64 + (l>>4)*16 .. +16.  One fragment = 1 KB contiguous.
__global__ __launch_bounds__(256) void transpose_pack(
    const int* __restrict__ W32, int8_t* __restrict__ Wt2, int K, int N) {
  __shared__ __align__(16) int8_t tile[64][80];
  const int t = threadIdx.x;
  const int n0 = blockIdx.x * 64;
  const int k0 = blockIdx.y * 64;
  const int ln = t & 63;
  const int wv = t >> 6;
#pragma unroll
  for (int it = 0; it < 16; ++it) {
    const int kk = wv * 16 + it;
    tile[ln][kk] = (int8_t)W32[(size_t)(k0 + kk) * N + n0 + ln];
  }
  __syncthreads();
  const int lane = ln;
  const int4 v = *(const int4*)&tile[wv * 16 + (lane & 15)][(lane >> 4) * 16];
  const int tn = n0 >> 8;
  const int kt = k0 >> 6;
  const int f = ((n0 >> 4) & 15) + wv;
  *(int4*)(Wt2 + (((size_t)(tn * 64 + kt) * 16 + f) * 64 + lane) * 16) = v;
}

// ---- int8 GEMM: BARRIER-FREE. Per-wave private LDS ring (each wave stages the ----
// ---- 8 A-frags it reads); B direct global->VGPR; waves fully self-paced.      ----
__global__ __launch_bounds__(512, 2) void gemm_i8(
    const int8_t* __restrict__ Xq2, const int8_t* __restrict__ Wt2,
    const float* __restrict__ xs, const float* __restrict__ wsc,
    const float* __restrict__ bias, float* __restrict__ C) {
  __shared__ __align__(16) int8_t lA[8][2][8192];  // 128 KB: per-wave 2-slot ring

  const int t = threadIdx.x;
  const int lane = t & 63;
  const int w = t >> 6;
  const int wr = w >> 2;  // 0..1 (M half: 128 rows)
  const int wc = w & 3;   // 0..3 (N quarter: 64 cols)
  const int fr = lane & 15;
  const int kg = lane >> 4;

  // bijective XCD swizzle: 1024 blocks = 8 XCD x (16 M x 8 N) rectangles
  const int bid = blockIdx.x;
  const int xcd = bid & 7;
  const int q = bid >> 3;
  const int tm = q & 15;
  const int tn = xcd * 8 + (q >> 4);
  const size_t rowA0 = (size_t)tm * BM;
  const size_t rowB0 = (size_t)tn * BN;

  // A source: the 8 fragments this wave reads (wr half), per-lane address
  const int8_t* aqB =
      Xq2 + (size_t)tm * 1048576 + wr * 8192 + (size_t)lane * 16;
  int8_t* lw = &lA[w][0][0];  // wave-uniform private LDS base

  // B fragment base for this wave: f = wc*4 + nj
  const int8_t* bq = Wt2 + (size_t)tn * 1048576 + wc * 4096 + (size_t)lane * 16;

  v4i acc[8][4] = {};
  v4i areg[8], breg[2][4];  // rings of 2

#define LD(dst, ptr)                                        \
  asm volatile("global_load_dwordx4 %0, %1, off"            \
               : "=v"(dst)                                  \
               : "v"(ptr)                                   \
               : "memory")

  // one batch = 8 A-stage gload_lds + 4 B loads = 12 VMEM ops
#define ISSUE(T, S)                                         \
  {                                                         \
    const int8_t* ap = aqB + (size_t)(T)*16384;             \
    int8_t* lp = lw + (S)*8192;                             \
    gload16(ap, lp);                                        \
    gload16(ap + 1024, lp + 1024);                          \
    gload16(ap + 2048, lp + 2048);                          \
    gload16(ap + 3072, lp + 3072);                          \
    gload16(ap + 4096, lp + 4096);                          \
    gload16(ap + 5120, lp + 5120);                          \
    gload16(ap + 6144, lp + 6144);                          \
    gload16(ap + 7168, lp + 7168);                          \
    const int8_t* bp = bq + (size_t)(T)*16384;              \
    LD(breg[S][0], bp);                                     \
    LD(breg[S][1], bp + 1024);                              \
    LD(breg[S][2], bp + 2048);                              \
    LD(breg[S][3], bp + 3072);                              \
  }

  // A fragment read from private region: lane-linear -> conflict-free
#define RD_A(MI, S)                                         \
  areg[MI] = *(const v4i*)(lw + (S)*8192 + (MI)*1024 + lane * 16);

#define SB __builtin_amdgcn_sched_barrier(0)

#define BODY(T, S)                                                            \
  {                                                                           \
    ISSUE(((T) + 1) & (NT - 1), (S) ^ 1); /* next batch first: gate never */  \
    SB;                                   /* drains (12 stay in flight) */    \
    asm volatile("s_waitcnt vmcnt(12)" ::: "memory"); /* batch T landed */    \
    SB;                                                                       \
    RD_A(0, S); RD_A(1, S); RD_A(2, S); RD_A(3, S);                           \
    SB;                                                                       \
    RD_A(4, S); RD_A(5, S); RD_A(6, S); RD_A(7, S);                           \
    SB;                                                                       \
    asm volatile("s_waitcnt lgkmcnt(4)" ::: "memory"); /* A0-3 ready */       \
    SB;                                                                       \
    __builtin_amdgcn_s_setprio(1);                                            \
    _Pragma("unroll") for (int mi = 0; mi < 4; ++mi)                          \
        _Pragma("unroll") for (int nj = 0; nj < 4; ++nj)                      \
            acc[mi][nj] = __builtin_amdgcn_mfma_i32_16x16x64_i8(              \
                areg[mi], breg[S][nj], acc[mi][nj], 0, 0, 0);                 \
    __builtin_amdgcn_s_setprio(0);                                            \
    asm volatile("s_waitcnt lgkmcnt(0)" ::: "memory"); /* A4-7 ready */       \
    SB;                                                                       \
    __builtin_amdgcn_s_setprio(1);                                            \
    _Pragma("unroll") for (int mi = 4; mi < 8; ++mi)                          \
        _Pragma("unroll") for (int nj = 0; nj < 4; ++nj)                      \
            acc[mi][nj] = __builtin_amdgcn_mfma_i32_16x16x64_i8(              \
                areg[mi], breg[S][nj], acc[mi][nj], 0, 0, 0);                 \
    __builtin_amdgcn_s_setprio(0);                                            \
  }

  // prologue: issue batch 0 (12 loads in flight)
  ISSUE(0, 0);

  for (int kt = 0; kt < NT; kt += 2) {
    BODY(kt, 0);
    BODY(kt + 1, 1);
  }
  // drain wrap-around prefetch so late writebacks can't clobber reused regs
  asm volatile("s_waitcnt vmcnt(0) lgkmcnt(0)" ::: "memory");
  SB;

  // epilogue: dequant + bias -> bf16-round -> f32 store
  // 16x16 C/D: col = lane&15, row = (lane>>4)*4 + reg
#pragma unroll
  for (int nj = 0; nj < 4; ++nj) {
    const int col_l = wc * 64 + nj * 16 + fr;
    const float wsv = wsc[rowB0 + col_l];
    const float bv = bias[rowB0 + col_l];
#pragma unroll
    for (int mi = 0; mi < 8; ++mi) {
#pragma unroll
      for (int r = 0; r < 4; ++r) {
        const size_t row = rowA0 + wr * 128 + mi * 16 + kg * 4 + r;
        const float f = (float)acc[mi][nj][r] * xs[row] * wsv + bv;
        C[row * GN + rowB0 + col_l] = __bfloat162float(__float2bfloat16(f));
      }
    }
  }
}

extern "C" void kernel_launch(void* const* d_in, const int* in_sizes, int n_in,
                              void* d_out, int out_size, void* d_ws, size_t ws_size,
                              hipStream_t stream) {
  const int M = GM, K = GK, N = GN;
  const float* x = (const float*)d_in[0];
  const int* W32 = (const int*)d_in[1];  // harness pushes integer inputs as int32
  const float* wsc = (const float*)d_in[2];
  const float* bias = (const float*)d_in[3];
  float* out = (float*)d_out;  // reference output dtype is float32 (bf16-rounded)

  // workspace layout: xs (16KB) | Xq2 (16MB packed) | Wt2 (64MB packed)
  float* xs = (float*)d_ws;
  int8_t* Xq2 = (int8_t*)d_ws + 16384;
  int8_t* Wt2 = (int8_t*)d_ws + 16384 + (size_t)M * K;

  transpose_pack<<<dim3(N / 64, K / 64), 256, 0, stream>>>(W32, Wt2, K, N);
  quant_rows<<<M, 256, 0, stream>>>(x, Xq2, xs, K);
  gemm_i8<<<dim3((M / BM) * (N / BN)), 512, 0, stream>>>(Xq2, Wt2, xs, wsc, bias,
                                                         out);
}